// Round 12
// baseline (347.313 us; speedup 1.0000x reference)
//
#include <hip/hip_runtime.h>
#include <hip/hip_bf16.h>

// ---------------------------------------------------------------------------
// REMSA fused block on MI355X.
// Shapes: B=4, N=4096, C=1024, H=16, D=64. M = B*N = 16384.
//
//   xb    = bf16(x)                                   [M,1024]
//   W2    = conv_w @ pw_w^T (prefused), b2 fused      [1024,1024]
//   qkvx  = xb @ [qkv_w | W2] + [qkv_b | b2]          [M,4096]  (gemmMain)
//   attn / depthwise3 epilogue (one kernel)           -> xcat [M,2048]
//   out   = xcat @ [out_w; tok_w] + (out_b+tok_b)     [M,1024]  (gemmMain K=2048)
//
// gemmMain v5 (occupancy experiment): 128x256 tile, BK=32, 8 waves (2Mx4N),
// per-wave 64x64 (4x4 16x16 frags, 64 acc VGPR), 3 LDS bufs x 24 KiB = 72 KiB
// -> 2 blocks/CU = 4 waves/SIMD (launch_bounds(512,4)).  Distance-2 staging
// via global_load_lds (3 loads/thread/tile), counted vmcnt(3) at tile end
// (never 0), ONE barrier/tile.  Sibling block on the CU fills MFMA pipe
// during this block's read/sync windows.  Bank swizzle: 16B chunk
// kc ^= (row>>1)&3 on global source + ds_read offsets (0 conflicts,
// verified rounds 4-10).
// ---------------------------------------------------------------------------

typedef __attribute__((ext_vector_type(8))) short sh8;
typedef __attribute__((ext_vector_type(4))) float f4;

__device__ __forceinline__ float bf2f(short s) {
  unsigned u = ((unsigned)(unsigned short)s) << 16;
  return __builtin_bit_cast(float, u);
}
__device__ __forceinline__ short f2bf(float f) {
  return __builtin_bit_cast(short, __float2bfloat16(f));
}
__device__ __forceinline__ void g2l16(const void* g, void* l) {
  __builtin_amdgcn_global_load_lds(
      (const __attribute__((address_space(1))) unsigned int*)g,
      (__attribute__((address_space(3))) unsigned int*)l, 16, 0, 0);
}

// --------------------------- f32 -> bf16 convert ---------------------------
__global__ __launch_bounds__(256) void cvt_f32_bf16(
    const float* __restrict__ src, short* __restrict__ dst, int n8) {
  int i = blockIdx.x * 256 + threadIdx.x;
  if (i >= n8) return;
  float4 a = ((const float4*)src)[i * 2];
  float4 b = ((const float4*)src)[i * 2 + 1];
  sh8 o;
  o[0] = f2bf(a.x); o[1] = f2bf(a.y); o[2] = f2bf(a.z); o[3] = f2bf(a.w);
  o[4] = f2bf(b.x); o[5] = f2bf(b.y); o[6] = f2bf(b.z); o[7] = f2bf(b.w);
  ((sh8*)dst)[i] = o;
}

// ------------------- transpose f32 (KxN) -> bf16 (N x ldd) -----------------
__global__ __launch_bounds__(256) void transpose_f32_bf16(
    const float* __restrict__ src, short* __restrict__ dst,
    int N, int ldd, int coff) {
  __shared__ float tile[32][33];
  int kb = blockIdx.y * 32, nb = blockIdx.x * 32;
  int tx = threadIdx.x, ty = threadIdx.y;
#pragma unroll
  for (int j = 0; j < 32; j += 8)
    tile[ty + j][tx] = src[(size_t)(kb + ty + j) * N + nb + tx];
  __syncthreads();
#pragma unroll
  for (int j = 0; j < 32; j += 8)
    dst[(size_t)(nb + ty + j) * ldd + coff + kb + tx] = f2bf(tile[tx][ty + j]);
}

// --------------------------- misc bias / dw prep ---------------------------
__global__ __launch_bounds__(256) void prep_misc(
    const float* __restrict__ pw_w, const float* __restrict__ conv_b,
    const float* __restrict__ pw_b, const float* __restrict__ qkv_b,
    const float* __restrict__ out_b, const float* __restrict__ tok_b,
    const float* __restrict__ dw_w, const float* __restrict__ dw_b,
    float* __restrict__ bias4, float* __restrict__ bcat,
    float* __restrict__ dw0, float* __restrict__ dw1,
    float* __restrict__ dw2, float* __restrict__ dwb) {
  int o = blockIdx.x;
  if (o < 1024) {
    float part = 0.f;
    for (int i = threadIdx.x; i < 1024; i += 256)
      part += pw_w[(size_t)o * 1024 + i] * conv_b[i];
#pragma unroll
    for (int off = 32; off >= 1; off >>= 1) part += __shfl_down(part, off);
    __shared__ float red[4];
    int wid = threadIdx.x >> 6, lane = threadIdx.x & 63;
    if (lane == 0) red[wid] = part;
    __syncthreads();
    if (threadIdx.x == 0) {
      float s = red[0] + red[1] + red[2] + red[3];
      bias4[3072 + o] = s + pw_b[o];
      bcat[o] = out_b[o] + tok_b[o];
      dw0[o] = dw_w[o * 3 + 0];
      dw1[o] = dw_w[o * 3 + 1];
      dw2[o] = dw_w[o * 3 + 2];
      dwb[o] = dw_b[o];
    }
  }
  if (threadIdx.x == 0) bias4[o] = qkv_b[o];
}

// --------------------- bf16 GEMM, 128x128 (prep only) ----------------------
template <int OUT_BF16>
__global__ __launch_bounds__(256, 2) void gemm128(
    const short* __restrict__ A, const short* __restrict__ Bt,
    void* __restrict__ Cp, const float* __restrict__ bias, int K, int ldc) {
  __shared__ short As[128 * 32];
  __shared__ short Bs[128 * 32];
  const int wid = threadIdx.x >> 6, lane = threadIdx.x & 63;
  const int bm = blockIdx.y, bn = blockIdx.x;
  const int wr = wid >> 1, wc = wid & 1;
  const size_t abase = (size_t)bm * 128 * K;
  const size_t bbase = (size_t)bn * 128 * K;
  const int r16 = lane & 15, ko = (lane >> 4) * 8;

  f4 acc[4][4] = {};

  for (int k0 = 0; k0 < K; k0 += 32) {
    __syncthreads();
#pragma unroll
    for (int c = 0; c < 2; ++c) {
      int ch = c * 256 + wid * 64 + lane;
      int row = ch >> 2, kc = (ch & 3) * 8;
      g2l16(A + abase + (size_t)row * K + k0 + kc, &As[ch * 8]);
      g2l16(Bt + bbase + (size_t)row * K + k0 + kc, &Bs[ch * 8]);
    }
    __syncthreads();
    sh8 af[4], bf[4];
#pragma unroll
    for (int i = 0; i < 4; ++i)
      af[i] = *(const sh8*)&As[(wr * 64 + i * 16 + r16) * 32 + ko];
#pragma unroll
    for (int j = 0; j < 4; ++j)
      bf[j] = *(const sh8*)&Bs[(wc * 64 + j * 16 + r16) * 32 + ko];
#pragma unroll
    for (int i = 0; i < 4; ++i)
#pragma unroll
      for (int j = 0; j < 4; ++j)
        acc[i][j] = __builtin_amdgcn_mfma_f32_16x16x32_bf16(af[i], bf[j],
                                                            acc[i][j], 0, 0, 0);
  }

  const int crow = wr * 64 + (lane >> 4) * 4;
  const int ccol = wc * 64 + r16;
#pragma unroll
  for (int i = 0; i < 4; ++i) {
#pragma unroll
    for (int j = 0; j < 4; ++j) {
      int col = bn * 128 + ccol + j * 16;
      float bv = bias ? bias[col] : 0.f;
#pragma unroll
      for (int r = 0; r < 4; ++r) {
        int row = bm * 128 + crow + i * 16 + r;
        float v = acc[i][j][r] + bv;
        if (OUT_BF16)
          ((short*)Cp)[(size_t)row * ldc + col] = f2bf(v);
        else
          ((float*)Cp)[(size_t)row * ldc + col] = v;
      }
    }
  }
}

// ---------- bf16 GEMM, 128x256 tile, 2 blocks/CU (4 waves/SIMD) ------------
// C[M,N] = A[M,K] @ Bt[N,K]^T + bias.  Grid 1D, nwg = (M/128)*(N/256),
// nwg % 8 == 0 (XCD swizzle).  512 threads = 8 waves (2M x 4N), per-wave
// 64x64 output (4x4 16x16 frags, 64 acc VGPR).  LDS: 3 bufs x (A 8K + B 16K)
// = 72 KiB -> 2 blocks/CU.  BK=32, NT=K/32.  Distance-2: during tile t stage
// tile t+2 into buf (t+2)%3 (its readers finished before end-of-(t-1)
// barrier).  3 loads/thread/tile; tile-end vmcnt(3) drains t+1's, leaves
// t+2's.  One barrier per tile; the sibling block hides the stall.
template <int OUT_BF16>
__global__ __launch_bounds__(512, 4) void gemmMain(
    const short* __restrict__ A, const short* __restrict__ Bt,
    void* __restrict__ Cp, const float* __restrict__ bias,
    int K, int ldc, int nbn) {
  __shared__ short lds[36864];  // 72 KiB: 3 bufs x 12288 shorts
  const int tid = threadIdx.x;
  const int lane = tid & 63, wid = tid >> 6;
  const int wr = wid >> 2, wc = wid & 3;
  const int r16 = lane & 15;
  const int kidx = ((lane >> 4) ^ ((r16 >> 1) & 3)) << 3;

  // XCD-aware swizzle (nwg % 8 == 0)
  const int cpx = gridDim.x >> 3;
  const int swz = (blockIdx.x & 7) * cpx + (blockIdx.x >> 3);
  const int bm = swz / nbn, bn = swz % nbn;

  const short* Ag = A + (size_t)bm * 128 * K;
  const short* Bg = Bt + (size_t)bn * 256 * K;

  // per-thread staging: 1 A chunk (512 total) + 2 B chunks (1024 total)
  int gA, lA, gB0, lB0, gB1, lB1;
  {
    int ch = tid, row = ch >> 2;
    int kc = (ch & 3) ^ ((row >> 1) & 3);
    gA = row * K + kc * 8;
    lA = ch * 8;
    int c0 = tid, r0 = c0 >> 2;
    int k0 = (c0 & 3) ^ ((r0 >> 1) & 3);
    gB0 = r0 * K + k0 * 8;
    lB0 = 4096 + c0 * 8;
    int c1 = 512 + tid, r1 = c1 >> 2;
    int k1 = (c1 & 3) ^ ((r1 >> 1) & 3);
    gB1 = r1 * K + k1 * 8;
    lB1 = 4096 + c1 * 8;
  }

  f4 acc[4][4] = {};
  const int NT = K >> 5;

#define STAGE3(KT, BUF)                                     \
  do {                                                      \
    short* lb = &lds[(BUF) * 12288];                        \
    const short* ga = Ag + (KT) * 32;                       \
    const short* gb = Bg + (KT) * 32;                       \
    g2l16(ga + gA, lb + lA);                                \
    g2l16(gb + gB0, lb + lB0);                              \
    g2l16(gb + gB1, lb + lB1);                              \
  } while (0)

  STAGE3(0, 0);
  STAGE3(1, 1);
  asm volatile("s_waitcnt vmcnt(3)" ::: "memory");  // tile 0 landed
  __builtin_amdgcn_sched_barrier(0);
  __builtin_amdgcn_s_barrier();
  __builtin_amdgcn_sched_barrier(0);

  int cb = 0;  // buf index of tile t
  for (int t = 0; t < NT; ++t) {
    int sb = cb + 2; if (sb >= 3) sb -= 3;
    const int kt = (t + 2 < NT) ? t + 2 : 0;  // dummy tail reload (uniform)
    STAGE3(kt, sb);

    const short* base = &lds[cb * 12288];
    sh8 af[4], bfr[4];
#pragma unroll
    for (int i = 0; i < 4; ++i)
      af[i] = *(const sh8*)&base[(wr * 64 + i * 16 + r16) * 32 + kidx];
#pragma unroll
    for (int j = 0; j < 4; ++j)
      bfr[j] = *(const sh8*)&base[4096 + (wc * 64 + j * 16 + r16) * 32 + kidx];

    __builtin_amdgcn_s_setprio(1);
#pragma unroll
    for (int i = 0; i < 4; ++i)
#pragma unroll
      for (int j = 0; j < 4; ++j)
        acc[i][j] = __builtin_amdgcn_mfma_f32_16x16x32_bf16(af[i], bfr[j],
                                                            acc[i][j], 0, 0, 0);
    __builtin_amdgcn_s_setprio(0);
    __builtin_amdgcn_sched_barrier(0);
    // drain tile t+1's 3 loads (t+2's 3 remain outstanding); never 0.
    asm volatile("s_waitcnt vmcnt(3)" ::: "memory");
    __builtin_amdgcn_sched_barrier(0);
    __builtin_amdgcn_s_barrier();
    __builtin_amdgcn_sched_barrier(0);
    cb = cb + 1; if (cb >= 3) cb -= 3;
  }
#undef STAGE3

  // C-write: j innermost -> contiguous 128B (bf16) / 256B (f32) per row.
  const int crow0 = bm * 128 + wr * 64 + (lane >> 4) * 4;
  const int ccol0 = bn * 256 + wc * 64 + r16;
  float bv[4];
#pragma unroll
  for (int j = 0; j < 4; ++j) bv[j] = bias ? bias[ccol0 + j * 16] : 0.f;
#pragma unroll
  for (int i = 0; i < 4; ++i) {
#pragma unroll
    for (int r = 0; r < 4; ++r) {
      size_t rowoff = (size_t)(crow0 + i * 16 + r) * ldc + ccol0;
#pragma unroll
      for (int j = 0; j < 4; ++j) {
        float v = acc[i][j][r] + bv[j];
        if (OUT_BF16)
          ((short*)Cp)[rowoff + j * 16] = f2bf(v);
        else
          ((float*)Cp)[rowoff + j * 16] = v;
      }
    }
  }
}

// ------------------ fused epilogue: attention + depthwise ------------------
// One block = 4 tokens.  attn reads qkvx cols 0-3071; dwconv reads cols
// 3072-4095 of rows t0-1..t0+4 (staged in LDS).  Writes xcat [M,2048].
__global__ __launch_bounds__(256) void epilogue(
    const short* __restrict__ qkvx, const float* __restrict__ pos_bias,
    const float* __restrict__ dw0, const float* __restrict__ dw1,
    const float* __restrict__ dw2, const float* __restrict__ dwb,
    short* __restrict__ xcat) {
  __shared__ short sq[4 * 3072];      // 4 tokens x cols 0-3071
  __shared__ short slice[6 * 1024];   // rows t0-1..t0+4 x cols 3072-4095
  int t0 = blockIdx.x * 4;
#pragma unroll
  for (int c = 0; c < 6; ++c) {
    int g = c * 256 + threadIdx.x;    // 1536 chunks = 4 tok x 384
    int tok = (g * 683) >> 18;        // g / 384 for g < 1536
    int off = g - tok * 384;
    ((sh8*)sq)[tok * 384 + off] =
        *(const sh8*)(qkvx + (size_t)(t0 + tok) * 4096 + off * 8);
  }
#pragma unroll
  for (int s = 0; s < 3; ++s) {
    int g = s * 256 + threadIdx.x;    // 768 chunks = 6 rows x 128
    int r = g >> 7, off = g & 127;
    int gr = t0 - 1 + r;
    sh8 v = {};
    if (gr >= 0 && gr < 16384)
      v = *(const sh8*)(qkvx + (size_t)gr * 4096 + 3072 + off * 8);
    ((sh8*)slice)[g] = v;
  }
  __syncthreads();

  int wid = threadIdx.x >> 6, lane = threadIdx.x & 63;
  int t = t0 + wid, n = t & 4095;
  int h = lane >> 2, sub = lane & 3;
  const short* base = sq + wid * 3072 + h * 192;

  float qf[64];
#pragma unroll
  for (int c = 0; c < 8; ++c) {
    sh8 v8 = *(const sh8*)(base + c * 8);
#pragma unroll
    for (int j = 0; j < 8; ++j) qf[c * 8 + j] = bf2f(v8[j]);
  }

  const float* pb = pos_bias + (size_t)n * 256 + h * 16 + sub * 4;
  float p[4];
  float m = -1e30f;
#pragma unroll
  for (int g4 = 0; g4 < 4; ++g4) {
    int g = sub * 4 + g4;
    const short* kk = sq + wid * 3072 + g * 192 + 64;
    float acc = 0.f;
#pragma unroll
    for (int c = 0; c < 8; ++c) {
      sh8 k8 = *(const sh8*)(kk + c * 8);
#pragma unroll
      for (int j = 0; j < 8; ++j) acc += qf[c * 8 + j] * bf2f(k8[j]);
    }
    p[g4] = acc * 0.125f + pb[g4];
    m = fmaxf(m, p[g4]);
  }
  m = fmaxf(m, __shfl_xor(m, 1));
  m = fmaxf(m, __shfl_xor(m, 2));
  float sum = 0.f;
#pragma unroll
  for (int g4 = 0; g4 < 4; ++g4) {
    p[g4] = __expf(p[g4] - m);
    sum += p[g4];
  }
  sum += __shfl_xor(sum, 1);
  sum += __shfl_xor(sum, 2);
  float inv = 1.0f / sum;
#pragma unroll
  for (int g4 = 0; g4 < 4; ++g4) p[g4] *= inv;

  float pall[16];
#pragma unroll
  for (int g = 0; g < 16; ++g)
    pall[g] = __shfl(p[g & 3], (lane & 60) | (g >> 2));

  float o[16] = {};
#pragma unroll
  for (int g = 0; g < 16; ++g) {
    const short* vv = sq + wid * 3072 + g * 192 + 128 + sub * 16;
    sh8 va = *(const sh8*)vv;
    sh8 vb = *(const sh8*)(vv + 8);
#pragma unroll
    for (int j = 0; j < 8; ++j) {
      o[j] += pall[g] * bf2f(va[j]);
      o[8 + j] += pall[g] * bf2f(vb[j]);
    }
  }
  sh8 oa, ob;
#pragma unroll
  for (int j = 0; j < 8; ++j) {
    oa[j] = f2bf(o[j]);
    ob[j] = f2bf(o[8 + j]);
  }
  short* dst = xcat + (size_t)t * 2048 + h * 64 + sub * 16;
  *(sh8*)dst = oa;
  *(sh8*)(dst + 8) = ob;

  // ---- depthwise conv from LDS slice: 2 outputs of 8 channels per thread --
#pragma unroll
  for (int it = 0; it < 2; ++it) {
    int w = it * 256 + threadIdx.x;   // 512 = 4 tok x 64 col-chunks
    int tok = w >> 7, co = (w & 127) * 8;
    int tt = t0 + tok, nn = tt & 4095;
    const short* lo8 = slice + tok * 1024 + co;
    const short* mi8 = lo8 + 1024;
    const short* hi8 = lo8 + 2048;
    sh8 lo = (nn > 0) ? *(const sh8*)lo8 : sh8{};
    sh8 mi = *(const sh8*)mi8;
    sh8 hi = (nn < 4095) ? *(const sh8*)hi8 : sh8{};
    sh8 out;
#pragma unroll
    for (int j = 0; j < 8; ++j) {
      float v = dw0[co + j] * bf2f(lo[j]) + dw1[co + j] * bf2f(mi[j]) +
                dw2[co + j] * bf2f(hi[j]) + dwb[co + j];
      out[j] = f2bf(v);
    }
    *(sh8*)(xcat + (size_t)tt * 2048 + 1024 + co) = out;
  }
}

// ---------------------------------------------------------------------------
extern "C" void kernel_launch(void* const* d_in, const int* in_sizes, int n_in,
                              void* d_out, int out_size, void* d_ws,
                              size_t ws_size, hipStream_t stream) {
  const float* x      = (const float*)d_in[0];
  const float* qkv_w  = (const float*)d_in[1];
  const float* qkv_b  = (const float*)d_in[2];
  const float* out_w  = (const float*)d_in[3];
  const float* out_b  = (const float*)d_in[4];
  const float* pos_b  = (const float*)d_in[5];
  const float* conv_w = (const float*)d_in[6];
  const float* conv_b = (const float*)d_in[7];
  const float* pw_w   = (const float*)d_in[8];
  const float* pw_b   = (const float*)d_in[9];
  const float* dw_w   = (const float*)d_in[10];
  const float* dw_b   = (const float*)d_in[11];
  const float* tok_w  = (const float*)d_in[12];
  const float* tok_b  = (const float*)d_in[13];

  const int M = 16384;
  char* ws = (char*)d_ws;
  size_t off = 0;
  auto alloc = [&](size_t bytes) -> void* {
    void* p = ws + off;
    off += (bytes + 255) & ~(size_t)255;
    return p;
  };
  short* xb    = (short*)alloc((size_t)M * 1024 * 2);
  short* wbig  = (short*)alloc((size_t)4096 * 1024 * 2);  // [qkv_w^T | W2^T]
  short* wcatT = (short*)alloc((size_t)1024 * 2048 * 2);
  short* convb = (short*)alloc((size_t)1024 * 1024 * 2);
  short* pwb   = (short*)alloc((size_t)1024 * 1024 * 2);
  short* qkvx  = (short*)alloc((size_t)M * 4096 * 2);
  short* xcat  = (short*)alloc((size_t)M * 2048 * 2);
  float* bias4 = (float*)alloc(4096 * 4);
  float* bcat  = (float*)alloc(1024 * 4);
  float* dw0   = (float*)alloc(1024 * 4);
  float* dw1   = (float*)alloc(1024 * 4);
  float* dw2   = (float*)alloc(1024 * 4);
  float* dwb   = (float*)alloc(1024 * 4);
  (void)ws_size; (void)in_sizes; (void)n_in; (void)out_size;

  // weight prep
  cvt_f32_bf16<<<8192, 256, 0, stream>>>(x, xb, M * 1024 / 8);
  cvt_f32_bf16<<<512, 256, 0, stream>>>(conv_w, convb, 1024 * 1024 / 8);
  cvt_f32_bf16<<<512, 256, 0, stream>>>(pw_w, pwb, 1024 * 1024 / 8);
  transpose_f32_bf16<<<dim3(96, 32), dim3(32, 8), 0, stream>>>(qkv_w, wbig, 3072, 1024, 0);
  transpose_f32_bf16<<<dim3(32, 32), dim3(32, 8), 0, stream>>>(out_w, wcatT, 1024, 2048, 0);
  transpose_f32_bf16<<<dim3(32, 32), dim3(32, 8), 0, stream>>>(tok_w, wcatT, 1024, 2048, 1024);
  prep_misc<<<3072, 256, 0, stream>>>(pw_w, conv_b, pw_b, qkv_b, out_b, tok_b,
                                      dw_w, dw_b, bias4, bcat, dw0, dw1, dw2, dwb);
  // W2^T[o][p] = sum_i pw_w[o][i] * conv_w[p][i] -> rows 3072+ of wbig
  gemm128<1><<<dim3(8, 8), 256, 0, stream>>>(pwb, convb, wbig + (size_t)3072 * 1024,
                                             nullptr, 1024, 1024);

  // fused qkv+conv GEMM: [M,1024] @ [4096,1024]^T -> [M,4096]
  gemmMain<1><<<2048, 512, 0, stream>>>(xb, wbig, qkvx, bias4, 1024, 4096, 16);

  // fused attention + depthwise epilogue
  epilogue<<<4096, 256, 0, stream>>>(qkvx, pos_b, dw0, dw1, dw2, dwb, xcat);

  // out = xcat @ [out_w; tok_w] + (out_b + tok_b)
  gemmMain<0><<<512, 512, 0, stream>>>(xcat, wcatT, d_out, bcat, 2048, 1024, 4);
}

// Round 13
// 330.998 us; speedup vs baseline: 1.0493x; 1.0493x over previous
//
#include <hip/hip_runtime.h>
#include <hip/hip_bf16.h>

// ---------------------------------------------------------------------------
// REMSA fused block on MI355X.
// Shapes: B=4, N=4096, C=1024, H=16, D=64. M = B*N = 16384.
//
//   xb    = bf16(x)                                   [M,1024]
//   W2    = conv_w @ pw_w^T (prefused), b2 fused      [1024,1024]
//   qkvx  = xb @ [qkv_w | W2] + [qkv_b | b2]          [M,4096]  (gemm8p)
//   attn / depthwise3 epilogue (one kernel)           -> xcat [M,2048]
//   out   = xcat @ [out_w; tok_w] + (out_b+tok_b)     [M,1024]  (gemm8p K=2048)
//
// gemm8p: m201-style 8-phase schedule. 256x256 tile, BK=64, 8 waves (2Mx4N),
// per-wave 128x64 (8x4 16x16 frags).  LDS 128 KiB = 2 bufs x 4 slots
// (A-k0, A-k1, B-k0, B-k1; each 256x32 bf16 = 16 KB).  4 phases per K-tile:
//   ph0: read af0-3+bfr (ks0)   | stage A-k1(t+1) -> other buf
//   ph1: read af4-7 (ks0)       | stage B-k1(t+1) -> other buf
//   ph2: read af0-3+bfr (ks1)   | stage A-k0(t+2) -> current buf (slot done)
//   ph3: read af4-7 (ks1)       | stage B-k0(t+2) -> current buf
// Each phase: reads; stage(2 loads); vmcnt(6); barrier; setprio(1); 16 MFMA;
// setprio(0); barrier.  Ledger: 1 stage-op/phase, every slot read >=5 phases
// after staging; vmcnt(6)+barrier per phase => block-wide all-but-newest-3
// ops landed => every read covered (incl. t=0 via prologue vmcnt+barrier).
// vmcnt never 0 in the loop.  Bank swizzle: 16B chunk kc ^= (row>>1)&3 on
// global source + ds_read offsets (0 conflicts, verified rounds 4-12).
// ---------------------------------------------------------------------------

typedef __attribute__((ext_vector_type(8))) short sh8;
typedef __attribute__((ext_vector_type(4))) float f4;

__device__ __forceinline__ float bf2f(short s) {
  unsigned u = ((unsigned)(unsigned short)s) << 16;
  return __builtin_bit_cast(float, u);
}
__device__ __forceinline__ short f2bf(float f) {
  return __builtin_bit_cast(short, __float2bfloat16(f));
}
__device__ __forceinline__ void g2l16(const void* g, void* l) {
  __builtin_amdgcn_global_load_lds(
      (const __attribute__((address_space(1))) unsigned int*)g,
      (__attribute__((address_space(3))) unsigned int*)l, 16, 0, 0);
}

// --------------------------- f32 -> bf16 convert ---------------------------
__global__ __launch_bounds__(256) void cvt_f32_bf16(
    const float* __restrict__ src, short* __restrict__ dst, int n8) {
  int i = blockIdx.x * 256 + threadIdx.x;
  if (i >= n8) return;
  float4 a = ((const float4*)src)[i * 2];
  float4 b = ((const float4*)src)[i * 2 + 1];
  sh8 o;
  o[0] = f2bf(a.x); o[1] = f2bf(a.y); o[2] = f2bf(a.z); o[3] = f2bf(a.w);
  o[4] = f2bf(b.x); o[5] = f2bf(b.y); o[6] = f2bf(b.z); o[7] = f2bf(b.w);
  ((sh8*)dst)[i] = o;
}

// ------------------- transpose f32 (KxN) -> bf16 (N x ldd) -----------------
__global__ __launch_bounds__(256) void transpose_f32_bf16(
    const float* __restrict__ src, short* __restrict__ dst,
    int N, int ldd, int coff) {
  __shared__ float tile[32][33];
  int kb = blockIdx.y * 32, nb = blockIdx.x * 32;
  int tx = threadIdx.x, ty = threadIdx.y;
#pragma unroll
  for (int j = 0; j < 32; j += 8)
    tile[ty + j][tx] = src[(size_t)(kb + ty + j) * N + nb + tx];
  __syncthreads();
#pragma unroll
  for (int j = 0; j < 32; j += 8)
    dst[(size_t)(nb + ty + j) * ldd + coff + kb + tx] = f2bf(tile[tx][ty + j]);
}

// --------------------------- misc bias / dw prep ---------------------------
__global__ __launch_bounds__(256) void prep_misc(
    const float* __restrict__ pw_w, const float* __restrict__ conv_b,
    const float* __restrict__ pw_b, const float* __restrict__ qkv_b,
    const float* __restrict__ out_b, const float* __restrict__ tok_b,
    const float* __restrict__ dw_w, const float* __restrict__ dw_b,
    float* __restrict__ bias4, float* __restrict__ bcat,
    float* __restrict__ dw0, float* __restrict__ dw1,
    float* __restrict__ dw2, float* __restrict__ dwb) {
  int o = blockIdx.x;
  if (o < 1024) {
    float part = 0.f;
    for (int i = threadIdx.x; i < 1024; i += 256)
      part += pw_w[(size_t)o * 1024 + i] * conv_b[i];
#pragma unroll
    for (int off = 32; off >= 1; off >>= 1) part += __shfl_down(part, off);
    __shared__ float red[4];
    int wid = threadIdx.x >> 6, lane = threadIdx.x & 63;
    if (lane == 0) red[wid] = part;
    __syncthreads();
    if (threadIdx.x == 0) {
      float s = red[0] + red[1] + red[2] + red[3];
      bias4[3072 + o] = s + pw_b[o];
      bcat[o] = out_b[o] + tok_b[o];
      dw0[o] = dw_w[o * 3 + 0];
      dw1[o] = dw_w[o * 3 + 1];
      dw2[o] = dw_w[o * 3 + 2];
      dwb[o] = dw_b[o];
    }
  }
  if (threadIdx.x == 0) bias4[o] = qkv_b[o];
}

// --------------------- bf16 GEMM, 128x128 (prep only) ----------------------
template <int OUT_BF16>
__global__ __launch_bounds__(256, 2) void gemm128(
    const short* __restrict__ A, const short* __restrict__ Bt,
    void* __restrict__ Cp, const float* __restrict__ bias, int K, int ldc) {
  __shared__ short As[128 * 32];
  __shared__ short Bs[128 * 32];
  const int wid = threadIdx.x >> 6, lane = threadIdx.x & 63;
  const int bm = blockIdx.y, bn = blockIdx.x;
  const int wr = wid >> 1, wc = wid & 1;
  const size_t abase = (size_t)bm * 128 * K;
  const size_t bbase = (size_t)bn * 128 * K;
  const int r16 = lane & 15, ko = (lane >> 4) * 8;

  f4 acc[4][4] = {};

  for (int k0 = 0; k0 < K; k0 += 32) {
    __syncthreads();
#pragma unroll
    for (int c = 0; c < 2; ++c) {
      int ch = c * 256 + wid * 64 + lane;
      int row = ch >> 2, kc = (ch & 3) * 8;
      g2l16(A + abase + (size_t)row * K + k0 + kc, &As[ch * 8]);
      g2l16(Bt + bbase + (size_t)row * K + k0 + kc, &Bs[ch * 8]);
    }
    __syncthreads();
    sh8 af[4], bf[4];
#pragma unroll
    for (int i = 0; i < 4; ++i)
      af[i] = *(const sh8*)&As[(wr * 64 + i * 16 + r16) * 32 + ko];
#pragma unroll
    for (int j = 0; j < 4; ++j)
      bf[j] = *(const sh8*)&Bs[(wc * 64 + j * 16 + r16) * 32 + ko];
#pragma unroll
    for (int i = 0; i < 4; ++i)
#pragma unroll
      for (int j = 0; j < 4; ++j)
        acc[i][j] = __builtin_amdgcn_mfma_f32_16x16x32_bf16(af[i], bf[j],
                                                            acc[i][j], 0, 0, 0);
  }

  const int crow = wr * 64 + (lane >> 4) * 4;
  const int ccol = wc * 64 + r16;
#pragma unroll
  for (int i = 0; i < 4; ++i) {
#pragma unroll
    for (int j = 0; j < 4; ++j) {
      int col = bn * 128 + ccol + j * 16;
      float bv = bias ? bias[col] : 0.f;
#pragma unroll
      for (int r = 0; r < 4; ++r) {
        int row = bm * 128 + crow + i * 16 + r;
        float v = acc[i][j][r] + bv;
        if (OUT_BF16)
          ((short*)Cp)[(size_t)row * ldc + col] = f2bf(v);
        else
          ((float*)Cp)[(size_t)row * ldc + col] = v;
      }
    }
  }
}

// ------------- bf16 GEMM, 256x256, 8-phase (m201-style) --------------------
template <int OUT_BF16>
__global__ __launch_bounds__(512, 2) void gemm8p(
    const short* __restrict__ A, const short* __restrict__ Bt,
    void* __restrict__ Cp, const float* __restrict__ bias,
    int K, int ldc, int nbn) {
  __shared__ short lds[65536];  // 128 KiB: 2 bufs x 4 slots x 8192 shorts
  const int tid = threadIdx.x;
  const int lane = tid & 63, wid = tid >> 6;
  const int wr = wid >> 2, wc = wid & 3;
  const int r16 = lane & 15;
  const int kidx = ((lane >> 4) ^ ((r16 >> 1) & 3)) << 3;

  // XCD-aware swizzle (nwg % 8 == 0)
  const int cpx = gridDim.x >> 3;
  const int swz = (blockIdx.x & 7) * cpx + (blockIdx.x >> 3);
  const int bm = swz / nbn, bn = swz % nbn;

  const short* Ag = A + (size_t)bm * 256 * K;
  const short* Bg = Bt + (size_t)bn * 256 * K;

  // per-thread staging offsets within a 256x32 half (verified r4-r12)
  int goff0, goff1, loff0, loff1;
  {
    int s0 = tid, row0 = s0 >> 2;
    int kc0 = (s0 & 3) ^ ((row0 >> 1) & 3);
    goff0 = row0 * K + kc0 * 8;
    loff0 = s0 * 8;
    int s1 = 512 + tid, row1 = s1 >> 2;
    int kc1 = (s1 & 3) ^ ((row1 >> 1) & 3);
    goff1 = row1 * K + kc1 * 8;
    loff1 = s1 * 8;
  }

  f4 acc[8][4] = {};
  const int NT = K >> 6;  // BK = 64, NT >= 2

  // one stage-op = one 256x32 half-operand (2 global_load_lds per thread)
#define SOP(GB, DS)                                         \
  do {                                                      \
    g2l16((GB) + goff0, (DS) + loff0);                      \
    g2l16((GB) + goff1, (DS) + loff1);                      \
  } while (0)

  // prologue: A-k0(0), B-k0(0), A-k1(0), B-k1(0), A-k0(1), B-k0(1)
  SOP(Ag, &lds[0]);
  SOP(Bg, &lds[16384]);
  SOP(Ag + 32, &lds[8192]);
  SOP(Bg + 32, &lds[24576]);
  SOP(Ag + 64, &lds[32768]);
  SOP(Bg + 64, &lds[32768 + 16384]);
  asm volatile("s_waitcnt vmcnt(6)" ::: "memory");
  __builtin_amdgcn_sched_barrier(0);
  __builtin_amdgcn_s_barrier();
  __builtin_amdgcn_sched_barrier(0);

  for (int t = 0; t < NT; ++t) {
    const int b = t & 1;
    const short* buf = &lds[b * 32768];
    short* bufN = &lds[(b ^ 1) * 32768];
    short* bufC = &lds[b * 32768];
    const int t1 = (t + 1 < NT) ? t + 1 : 0;  // dummy tail: uniform ledger
    const int t2 = (t + 2 < NT) ? t + 2 : 0;

    sh8 af[8], bfr[4];

    // ========== ph0: af0-3 + bfr (ks0) | stage A-k1(t+1) ==========
#pragma unroll
    for (int i = 0; i < 4; ++i)
      af[i] = *(const sh8*)&buf[(wr * 128 + i * 16 + r16) * 32 + kidx];
#pragma unroll
    for (int j = 0; j < 4; ++j)
      bfr[j] = *(const sh8*)&buf[16384 + (wc * 64 + j * 16 + r16) * 32 + kidx];
    SOP(Ag + t1 * 64 + 32, bufN + 8192);
    asm volatile("s_waitcnt vmcnt(6)" ::: "memory");
    __builtin_amdgcn_sched_barrier(0);
    __builtin_amdgcn_s_barrier();
    __builtin_amdgcn_sched_barrier(0);
    __builtin_amdgcn_s_setprio(1);
#pragma unroll
    for (int i = 0; i < 4; ++i)
#pragma unroll
      for (int j = 0; j < 4; ++j)
        acc[i][j] = __builtin_amdgcn_mfma_f32_16x16x32_bf16(af[i], bfr[j],
                                                            acc[i][j], 0, 0, 0);
    __builtin_amdgcn_s_setprio(0);
    __builtin_amdgcn_sched_barrier(0);
    __builtin_amdgcn_s_barrier();
    __builtin_amdgcn_sched_barrier(0);

    // ========== ph1: af4-7 (ks0) | stage B-k1(t+1) ==========
#pragma unroll
    for (int i = 4; i < 8; ++i)
      af[i] = *(const sh8*)&buf[(wr * 128 + i * 16 + r16) * 32 + kidx];
    SOP(Bg + t1 * 64 + 32, bufN + 24576);
    asm volatile("s_waitcnt vmcnt(6)" ::: "memory");
    __builtin_amdgcn_sched_barrier(0);
    __builtin_amdgcn_s_barrier();
    __builtin_amdgcn_sched_barrier(0);
    __builtin_amdgcn_s_setprio(1);
#pragma unroll
    for (int i = 4; i < 8; ++i)
#pragma unroll
      for (int j = 0; j < 4; ++j)
        acc[i][j] = __builtin_amdgcn_mfma_f32_16x16x32_bf16(af[i], bfr[j],
                                                            acc[i][j], 0, 0, 0);
    __builtin_amdgcn_s_setprio(0);
    __builtin_amdgcn_sched_barrier(0);
    __builtin_amdgcn_s_barrier();
    __builtin_amdgcn_sched_barrier(0);

    // ========== ph2: af0-3 + bfr (ks1) | stage A-k0(t+2) ==========
#pragma unroll
    for (int i = 0; i < 4; ++i)
      af[i] = *(const sh8*)&buf[8192 + (wr * 128 + i * 16 + r16) * 32 + kidx];
#pragma unroll
    for (int j = 0; j < 4; ++j)
      bfr[j] = *(const sh8*)&buf[24576 + (wc * 64 + j * 16 + r16) * 32 + kidx];
    SOP(Ag + t2 * 64, bufC);
    asm volatile("s_waitcnt vmcnt(6)" ::: "memory");
    __builtin_amdgcn_sched_barrier(0);
    __builtin_amdgcn_s_barrier();
    __builtin_amdgcn_sched_barrier(0);
    __builtin_amdgcn_s_setprio(1);
#pragma unroll
    for (int i = 0; i < 4; ++i)
#pragma unroll
      for (int j = 0; j < 4; ++j)
        acc[i][j] = __builtin_amdgcn_mfma_f32_16x16x32_bf16(af[i], bfr[j],
                                                            acc[i][j], 0, 0, 0);
    __builtin_amdgcn_s_setprio(0);
    __builtin_amdgcn_sched_barrier(0);
    __builtin_amdgcn_s_barrier();
    __builtin_amdgcn_sched_barrier(0);

    // ========== ph3: af4-7 (ks1) | stage B-k0(t+2) ==========
#pragma unroll
    for (int i = 4; i < 8; ++i)
      af[i] = *(const sh8*)&buf[8192 + (wr * 128 + i * 16 + r16) * 32 + kidx];
    SOP(Bg + t2 * 64, bufC + 16384);
    asm volatile("s_waitcnt vmcnt(6)" ::: "memory");
    __builtin_amdgcn_sched_barrier(0);
    __builtin_amdgcn_s_barrier();
    __builtin_amdgcn_sched_barrier(0);
    __builtin_amdgcn_s_setprio(1);
#pragma unroll
    for (int i = 4; i < 8; ++i)
#pragma unroll
      for (int j = 0; j < 4; ++j)
        acc[i][j] = __builtin_amdgcn_mfma_f32_16x16x32_bf16(af[i], bfr[j],
                                                            acc[i][j], 0, 0, 0);
    __builtin_amdgcn_s_setprio(0);
    __builtin_amdgcn_sched_barrier(0);
    __builtin_amdgcn_s_barrier();
    __builtin_amdgcn_sched_barrier(0);
  }
#undef SOP

  // C-write: j innermost -> contiguous 128B (bf16) / 256B (f32) per row.
  const int crow0 = bm * 256 + wr * 128 + (lane >> 4) * 4;
  const int ccol0 = bn * 256 + wc * 64 + r16;
  float bv[4];
#pragma unroll
  for (int j = 0; j < 4; ++j) bv[j] = bias ? bias[ccol0 + j * 16] : 0.f;
#pragma unroll
  for (int i = 0; i < 8; ++i) {
#pragma unroll
    for (int r = 0; r < 4; ++r) {
      size_t rowoff = (size_t)(crow0 + i * 16 + r) * ldc + ccol0;
#pragma unroll
      for (int j = 0; j < 4; ++j) {
        float v = acc[i][j][r] + bv[j];
        if (OUT_BF16)
          ((short*)Cp)[rowoff + j * 16] = f2bf(v);
        else
          ((float*)Cp)[rowoff + j * 16] = v;
      }
    }
  }
}

// ------------------ fused epilogue: attention + depthwise ------------------
__global__ __launch_bounds__(256) void epilogue(
    const short* __restrict__ qkvx, const float* __restrict__ pos_bias,
    const float* __restrict__ dw0, const float* __restrict__ dw1,
    const float* __restrict__ dw2, const float* __restrict__ dwb,
    short* __restrict__ xcat) {
  __shared__ short sq[4 * 3072];      // 4 tokens x cols 0-3071
  __shared__ short slice[6 * 1024];   // rows t0-1..t0+4 x cols 3072-4095
  int t0 = blockIdx.x * 4;
#pragma unroll
  for (int c = 0; c < 6; ++c) {
    int g = c * 256 + threadIdx.x;    // 1536 chunks = 4 tok x 384
    int tok = (g * 683) >> 18;        // g / 384 for g < 1536
    int off = g - tok * 384;
    ((sh8*)sq)[tok * 384 + off] =
        *(const sh8*)(qkvx + (size_t)(t0 + tok) * 4096 + off * 8);
  }
#pragma unroll
  for (int s = 0; s < 3; ++s) {
    int g = s * 256 + threadIdx.x;    // 768 chunks = 6 rows x 128
    int r = g >> 7, off = g & 127;
    int gr = t0 - 1 + r;
    sh8 v = {};
    if (gr >= 0 && gr < 16384)
      v = *(const sh8*)(qkvx + (size_t)gr * 4096 + 3072 + off * 8);
    ((sh8*)slice)[g] = v;
  }
  __syncthreads();

  int wid = threadIdx.x >> 6, lane = threadIdx.x & 63;
  int t = t0 + wid, n = t & 4095;
  int h = lane >> 2, sub = lane & 3;
  const short* base = sq + wid * 3072 + h * 192;

  float qf[64];
#pragma unroll
  for (int c = 0; c < 8; ++c) {
    sh8 v8 = *(const sh8*)(base + c * 8);
#pragma unroll
    for (int j = 0; j < 8; ++j) qf[c * 8 + j] = bf2f(v8[j]);
  }

  const float* pb = pos_bias + (size_t)n * 256 + h * 16 + sub * 4;
  float p[4];
  float m = -1e30f;
#pragma unroll
  for (int g4 = 0; g4 < 4; ++g4) {
    int g = sub * 4 + g4;
    const short* kk = sq + wid * 3072 + g * 192 + 64;
    float acc = 0.f;
#pragma unroll
    for (int c = 0; c < 8; ++c) {
      sh8 k8 = *(const sh8*)(kk + c * 8);
#pragma unroll
      for (int j = 0; j < 8; ++j) acc += qf[c * 8 + j] * bf2f(k8[j]);
    }
    p[g4] = acc * 0.125f + pb[g4];
    m = fmaxf(m, p[g4]);
  }
  m = fmaxf(m, __shfl_xor(m, 1));
  m = fmaxf(m, __shfl_xor(m, 2));
  float sum = 0.f;
#pragma unroll
  for (int g4 = 0; g4 < 4; ++g4) {
    p[g4] = __expf(p[g4] - m);
    sum += p[g4];
  }
  sum += __shfl_xor(sum, 1);
  sum += __shfl_xor(sum, 2);
  float inv = 1.0f / sum;
#pragma unroll
  for (int g4 = 0; g4 < 4; ++g4) p[g4] *= inv;

  float pall[16];
#pragma unroll
  for (int g = 0; g < 16; ++g)
    pall[g] = __shfl(p[g & 3], (lane & 60) | (g >> 2));

  float o[16] = {};
#pragma unroll
  for (int g = 0; g < 16; ++g) {
    const short* vv = sq + wid * 3072 + g * 192 + 128 + sub * 16;
    sh8 va = *(const sh8*)vv;
    sh8 vb = *(const sh8*)(vv + 8);
#pragma unroll
    for (int j = 0; j < 8; ++j) {
      o[j] += pall[g] * bf2f(va[j]);
      o[8 + j] += pall[g] * bf2f(vb[j]);
    }
  }
  sh8 oa, ob;
#pragma unroll
  for (int j = 0; j < 8; ++j) {
    oa[j] = f2bf(o[j]);
    ob[j] = f2bf(o[8 + j]);
  }
  short* dst = xcat + (size_t)t * 2048 + h * 64 + sub * 16;
  *(sh8*)dst = oa;
  *(sh8*)(dst + 8) = ob;

#pragma unroll
  for (int it = 0; it < 2; ++it) {
    int w = it * 256 + threadIdx.x;   // 512 = 4 tok x 64 col-chunks
    int tok = w >> 7, co = (w & 127) * 8;
    int tt = t0 + tok, nn = tt & 4095;
    const short* lo8 = slice + tok * 1024 + co;
    const short* mi8 = lo8 + 1024;
    const short* hi8 = lo8 + 2048;
    sh8 lo = (nn > 0) ? *(const sh8*)lo8 : sh8{};
    sh8 mi = *(const sh8*)mi8;
    sh8 hi = (nn < 4095) ? *(const sh8*)hi8 : sh8{};
    sh8 out;
#pragma unroll
    for (int j = 0; j < 8; ++j) {
      float v = dw0[co + j] * bf2f(lo[j]) + dw1[co + j] * bf2f(mi[j]) +
                dw2[co + j] * bf2f(hi[j]) + dwb[co + j];
      out[j] = f2bf(v);
    }
    *(sh8*)(xcat + (size_t)tt * 2048 + 1024 + co) = out;
  }
}

// ---------------------------------------------------------------------------
extern "C" void kernel_launch(void* const* d_in, const int* in_sizes, int n_in,
                              void* d_out, int out_size, void* d_ws,
                              size_t ws_size, hipStream_t stream) {
  const float* x      = (const float*)d_in[0];
  const float* qkv_w  = (const float*)d_in[1];
  const float* qkv_b  = (const float*)d_in[2];
  const float* out_w  = (const float*)d_in[3];
  const float* out_b  = (const float*)d_in[4];
  const float* pos_b  = (const float*)d_in[5];
  const float* conv_w = (const float*)d_in[6];
  const float* conv_b = (const float*)d_in[7];
  const float* pw_w   = (const float*)d_in[8];
  const float* pw_b   = (const float*)d_in[9];
  const float* dw_w   = (const float*)d_in[10];
  const float* dw_b   = (const float*)d_in[11];
  const float* tok_w  = (const float*)d_in[12];
  const float* tok_b  = (const float*)d_in[13];

  const int M = 16384;
  char* ws = (char*)d_ws;
  size_t off = 0;
  auto alloc = [&](size_t bytes) -> void* {
    void* p = ws + off;
    off += (bytes + 255) & ~(size_t)255;
    return p;
  };
  short* xb    = (short*)alloc((size_t)M * 1024 * 2);
  short* wbig  = (short*)alloc((size_t)4096 * 1024 * 2);  // [qkv_w^T | W2^T]
  short* wcatT = (short*)alloc((size_t)1024 * 2048 * 2);
  short* convb = (short*)alloc((size_t)1024 * 1024 * 2);
  short* pwb   = (short*)alloc((size_t)1024 * 1024 * 2);
  short* qkvx  = (short*)alloc((size_t)M * 4096 * 2);
  short* xcat  = (short*)alloc((size_t)M * 2048 * 2);
  float* bias4 = (float*)alloc(4096 * 4);
  float* bcat  = (float*)alloc(1024 * 4);
  float* dw0   = (float*)alloc(1024 * 4);
  float* dw1   = (float*)alloc(1024 * 4);
  float* dw2   = (float*)alloc(1024 * 4);
  float* dwb   = (float*)alloc(1024 * 4);
  (void)ws_size; (void)in_sizes; (void)n_in; (void)out_size;

  // weight prep
  cvt_f32_bf16<<<8192, 256, 0, stream>>>(x, xb, M * 1024 / 8);
  cvt_f32_bf16<<<512, 256, 0, stream>>>(conv_w, convb, 1024 * 1024 / 8);
  cvt_f32_bf16<<<512, 256, 0, stream>>>(pw_w, pwb, 1024 * 1024 / 8);
  transpose_f32_bf16<<<dim3(96, 32), dim3(32, 8), 0, stream>>>(qkv_w, wbig, 3072, 1024, 0);
  transpose_f32_bf16<<<dim3(32, 32), dim3(32, 8), 0, stream>>>(out_w, wcatT, 1024, 2048, 0);
  transpose_f32_bf16<<<dim3(32, 32), dim3(32, 8), 0, stream>>>(tok_w, wcatT, 1024, 2048, 1024);
  prep_misc<<<3072, 256, 0, stream>>>(pw_w, conv_b, pw_b, qkv_b, out_b, tok_b,
                                      dw_w, dw_b, bias4, bcat, dw0, dw1, dw2, dwb);
  // W2^T[o][p] = sum_i pw_w[o][i] * conv_w[p][i] -> rows 3072+ of wbig
  gemm128<1><<<dim3(8, 8), 256, 0, stream>>>(pwb, convb, wbig + (size_t)3072 * 1024,
                                             nullptr, 1024, 1024);

  // fused qkv+conv GEMM: [M,1024] @ [4096,1024]^T -> [M,4096]
  gemm8p<1><<<1024, 512, 0, stream>>>(xb, wbig, qkvx, bias4, 1024, 4096, 16);

  // fused attention + depthwise epilogue
  epilogue<<<4096, 256, 0, stream>>>(qkvx, pos_b, dw0, dw1, dw2, dwb, xcat);

  // out = xcat @ [out_w; tok_w] + (out_b + tok_b)
  gemm8p<0><<<256, 512, 0, stream>>>(xcat, wcatT, d_out, bcat, 2048, 1024, 4);
}

// Round 15
// 326.352 us; speedup vs baseline: 1.0642x; 1.0142x over previous
//
#include <hip/hip_runtime.h>
#include <hip/hip_bf16.h>

// ---------------------------------------------------------------------------
// REMSA fused block on MI355X.
// Shapes: B=4, N=4096, C=1024, H=16, D=64. M = B*N = 16384.
//
//   xb    = bf16(x)                                   [M,1024]
//   W2    = conv_w @ pw_w^T (prefused), b2 fused      [1024,1024]
//   qkvx  = xb @ [qkv_w | W2] + [qkv_b | b2]          [M,4096]  (gemm8p)
//   attn / depthwise3 epilogue (one kernel)           -> xcat [M,2048]
//   out   = xcat @ [out_w; tok_w] + (out_b+tok_b)     [M,1024]  (gemm8p K=2048)
//
// gemm8p v2 (faithful T3+T4): 256x256, BK=64, 8 waves, LDS 2 bufs x 4 slots
// (s0=A-k0, s1=A-k1, s2=B-k0, s3=B-k1; 8192 shorts each).  4 phases/tile:
//   ph0: read af0-3+bfr(ks0) | stage A-k1(t+1),B-k1(t+1) -> next buf s1,s3
//   ph1: read af4-7(ks0)     | stage B-k0(t+2) -> cur s2 (freed after ph0)
//   ph2: read af0-3+bfr(ks1) | stage A-k0(t+2) -> cur s0 (freed after ph1)
//   ph3: read af4-7(ks1)     | vmcnt(4)  <- ONLY wait in the tile, never 0
// Each phase: reads; stage; barrier; setprio(1); 16 MFMA; setprio(0); barrier.
// Ledger: 8 loads/tile (4-2-2-0).  End-of-tile vmcnt(4) leaves ph1+ph2's
// t+2 loads in flight, drains ph0's t+1 loads and all earlier => every slot
// landed block-wide before its first read.  Stage-issues always follow the
// barrier retiring that slot's readers (DMA cannot write before issue).
// Bank swizzle: kc ^= (row>>1)&3 on global source + ds_read offsets
// (0 conflicts, verified rounds 4-13).
// ---------------------------------------------------------------------------

typedef __attribute__((ext_vector_type(8))) short sh8;
typedef __attribute__((ext_vector_type(4))) float f4;

__device__ __forceinline__ float bf2f(short s) {
  unsigned u = ((unsigned)(unsigned short)s) << 16;
  return __builtin_bit_cast(float, u);
}
__device__ __forceinline__ short f2bf(float f) {
  return __builtin_bit_cast(short, __float2bfloat16(f));
}
__device__ __forceinline__ void g2l16(const void* g, void* l) {
  __builtin_amdgcn_global_load_lds(
      (const __attribute__((address_space(1))) unsigned int*)g,
      (__attribute__((address_space(3))) unsigned int*)l, 16, 0, 0);
}

// ---------------- f32 -> bf16 convert (x, conv_w, pw_w in one) -------------
__global__ __launch_bounds__(256) void cvt3(
    const float* __restrict__ x, const float* __restrict__ conv_w,
    const float* __restrict__ pw_w, short* __restrict__ xb,
    short* __restrict__ convb, short* __restrict__ pwb) {
  int i = blockIdx.x * 256 + threadIdx.x;  // 9216*256 = 2359296 chunks
  const float* src;
  short* dst;
  int off;
  if (i < 2097152) {
    src = x; dst = xb; off = i;
  } else if (i < 2228224) {
    src = conv_w; dst = convb; off = i - 2097152;
  } else {
    src = pw_w; dst = pwb; off = i - 2228224;
  }
  float4 a = ((const float4*)src)[off * 2];
  float4 b = ((const float4*)src)[off * 2 + 1];
  sh8 o;
  o[0] = f2bf(a.x); o[1] = f2bf(a.y); o[2] = f2bf(a.z); o[3] = f2bf(a.w);
  o[4] = f2bf(b.x); o[5] = f2bf(b.y); o[6] = f2bf(b.z); o[7] = f2bf(b.w);
  ((sh8*)dst)[off] = o;
}

// ------------------- transpose f32 (KxN) -> bf16 (N x ldd) -----------------
__global__ __launch_bounds__(256) void transpose_f32_bf16(
    const float* __restrict__ src, short* __restrict__ dst,
    int N, int ldd, int coff) {
  __shared__ float tile[32][33];
  int kb = blockIdx.y * 32, nb = blockIdx.x * 32;
  int tx = threadIdx.x, ty = threadIdx.y;
#pragma unroll
  for (int j = 0; j < 32; j += 8)
    tile[ty + j][tx] = src[(size_t)(kb + ty + j) * N + nb + tx];
  __syncthreads();
#pragma unroll
  for (int j = 0; j < 32; j += 8)
    dst[(size_t)(nb + ty + j) * ldd + coff + kb + tx] = f2bf(tile[tx][ty + j]);
}

// ------------- transpose out_w (z=0) and tok_w (z=1) into wcatT ------------
__global__ __launch_bounds__(256) void transpose2(
    const float* __restrict__ out_w, const float* __restrict__ tok_w,
    short* __restrict__ dst) {
  __shared__ float tile[32][33];
  const float* src = blockIdx.z ? tok_w : out_w;
  int coff = blockIdx.z ? 1024 : 0;
  int kb = blockIdx.y * 32, nb = blockIdx.x * 32;
  int tx = threadIdx.x, ty = threadIdx.y;
#pragma unroll
  for (int j = 0; j < 32; j += 8)
    tile[ty + j][tx] = src[(size_t)(kb + ty + j) * 1024 + nb + tx];
  __syncthreads();
#pragma unroll
  for (int j = 0; j < 32; j += 8)
    dst[(size_t)(nb + ty + j) * 2048 + coff + kb + tx] = f2bf(tile[tx][ty + j]);
}

// --------------------------- misc bias / dw prep ---------------------------
__global__ __launch_bounds__(256) void prep_misc(
    const float* __restrict__ pw_w, const float* __restrict__ conv_b,
    const float* __restrict__ pw_b, const float* __restrict__ qkv_b,
    const float* __restrict__ out_b, const float* __restrict__ tok_b,
    const float* __restrict__ dw_w, const float* __restrict__ dw_b,
    float* __restrict__ bias4, float* __restrict__ bcat,
    float* __restrict__ dw0, float* __restrict__ dw1,
    float* __restrict__ dw2, float* __restrict__ dwb) {
  int o = blockIdx.x;
  if (o < 1024) {
    float part = 0.f;
    for (int i = threadIdx.x; i < 1024; i += 256)
      part += pw_w[(size_t)o * 1024 + i] * conv_b[i];
#pragma unroll
    for (int off = 32; off >= 1; off >>= 1) part += __shfl_down(part, off);
    __shared__ float red[4];
    int wid = threadIdx.x >> 6, lane = threadIdx.x & 63;
    if (lane == 0) red[wid] = part;
    __syncthreads();
    if (threadIdx.x == 0) {
      float s = red[0] + red[1] + red[2] + red[3];
      bias4[3072 + o] = s + pw_b[o];
      bcat[o] = out_b[o] + tok_b[o];
      dw0[o] = dw_w[o * 3 + 0];
      dw1[o] = dw_w[o * 3 + 1];
      dw2[o] = dw_w[o * 3 + 2];
      dwb[o] = dw_b[o];
    }
  }
  if (threadIdx.x == 0) bias4[o] = qkv_b[o];
}

// --------------------- bf16 GEMM, 128x128 (prep only) ----------------------
template <int OUT_BF16>
__global__ __launch_bounds__(256, 2) void gemm128(
    const short* __restrict__ A, const short* __restrict__ Bt,
    void* __restrict__ Cp, const float* __restrict__ bias, int K, int ldc) {
  __shared__ short As[128 * 32];
  __shared__ short Bs[128 * 32];
  const int wid = threadIdx.x >> 6, lane = threadIdx.x & 63;
  const int bm = blockIdx.y, bn = blockIdx.x;
  const int wr = wid >> 1, wc = wid & 1;
  const size_t abase = (size_t)bm * 128 * K;
  const size_t bbase = (size_t)bn * 128 * K;
  const int r16 = lane & 15, ko = (lane >> 4) * 8;

  f4 acc[4][4] = {};

  for (int k0 = 0; k0 < K; k0 += 32) {
    __syncthreads();
#pragma unroll
    for (int c = 0; c < 2; ++c) {
      int ch = c * 256 + wid * 64 + lane;
      int row = ch >> 2, kc = (ch & 3) * 8;
      g2l16(A + abase + (size_t)row * K + k0 + kc, &As[ch * 8]);
      g2l16(Bt + bbase + (size_t)row * K + k0 + kc, &Bs[ch * 8]);
    }
    __syncthreads();
    sh8 af[4], bf[4];
#pragma unroll
    for (int i = 0; i < 4; ++i)
      af[i] = *(const sh8*)&As[(wr * 64 + i * 16 + r16) * 32 + ko];
#pragma unroll
    for (int j = 0; j < 4; ++j)
      bf[j] = *(const sh8*)&Bs[(wc * 64 + j * 16 + r16) * 32 + ko];
#pragma unroll
    for (int i = 0; i < 4; ++i)
#pragma unroll
      for (int j = 0; j < 4; ++j)
        acc[i][j] = __builtin_amdgcn_mfma_f32_16x16x32_bf16(af[i], bf[j],
                                                            acc[i][j], 0, 0, 0);
  }

  const int crow = wr * 64 + (lane >> 4) * 4;
  const int ccol = wc * 64 + r16;
#pragma unroll
  for (int i = 0; i < 4; ++i) {
#pragma unroll
    for (int j = 0; j < 4; ++j) {
      int col = bn * 128 + ccol + j * 16;
      float bv = bias ? bias[col] : 0.f;
#pragma unroll
      for (int r = 0; r < 4; ++r) {
        int row = bm * 128 + crow + i * 16 + r;
        float v = acc[i][j][r] + bv;
        if (OUT_BF16)
          ((short*)Cp)[(size_t)row * ldc + col] = f2bf(v);
        else
          ((float*)Cp)[(size_t)row * ldc + col] = v;
      }
    }
  }
}

// -------- bf16 GEMM, 256x256, 8-phase with single counted vmcnt/tile -------
template <int OUT_BF16>
__global__ __launch_bounds__(512, 2) void gemm8p(
    const short* __restrict__ A, const short* __restrict__ Bt,
    void* __restrict__ Cp, const float* __restrict__ bias,
    int K, int ldc, int nbn) {
  __shared__ short lds[65536];  // 2 bufs x {s0:A-k0, s1:A-k1, s2:B-k0, s3:B-k1}
  const int tid = threadIdx.x;
  const int lane = tid & 63, wid = tid >> 6;
  const int wr = wid >> 2, wc = wid & 3;
  const int r16 = lane & 15;
  const int kidx = ((lane >> 4) ^ ((r16 >> 1) & 3)) << 3;

  // XCD-aware swizzle (nwg % 8 == 0)
  const int cpx = gridDim.x >> 3;
  const int swz = (blockIdx.x & 7) * cpx + (blockIdx.x >> 3);
  const int bm = swz / nbn, bn = swz % nbn;

  const short* Ag = A + (size_t)bm * 256 * K;
  const short* Bg = Bt + (size_t)bn * 256 * K;

  int goff0, goff1, loff0, loff1;
  {
    int s0 = tid, row0 = s0 >> 2;
    int kc0 = (s0 & 3) ^ ((row0 >> 1) & 3);
    goff0 = row0 * K + kc0 * 8;
    loff0 = s0 * 8;
    int s1 = 512 + tid, row1 = s1 >> 2;
    int kc1 = (s1 & 3) ^ ((row1 >> 1) & 3);
    goff1 = row1 * K + kc1 * 8;
    loff1 = s1 * 8;
  }

  f4 acc[8][4] = {};
  const int NT = K >> 6;  // BK = 64, NT >= 2

#define SOP(GB, DS)                                         \
  do {                                                      \
    g2l16((GB) + goff0, (DS) + loff0);                      \
    g2l16((GB) + goff1, (DS) + loff1);                      \
  } while (0)

#define PHASE_SYNC()                                        \
  do {                                                      \
    __builtin_amdgcn_sched_barrier(0);                      \
    __builtin_amdgcn_s_barrier();                           \
    __builtin_amdgcn_sched_barrier(0);                      \
  } while (0)

  // prologue: tile0 all 4 slots, then tile1 {B-k0, A-k0}.  12 loads.
  {
    short* b0 = &lds[0];
    short* b1 = &lds[32768];
    SOP(Ag, b0 + 0);            // A-k0(0)
    SOP(Bg, b0 + 16384);        // B-k0(0)
    SOP(Ag + 32, b0 + 8192);    // A-k1(0)
    SOP(Bg + 32, b0 + 24576);   // B-k1(0)
    SOP(Bg + 64, b1 + 16384);   // B-k0(1)
    SOP(Ag + 64, b1 + 0);       // A-k0(1)
  }
  asm volatile("s_waitcnt vmcnt(4)" ::: "memory");  // tile0 landed
  PHASE_SYNC();

  for (int t = 0; t < NT; ++t) {
    const int b = t & 1;
    const short* buf = &lds[b * 32768];
    short* bufC = &lds[b * 32768];
    short* bufN = &lds[(b ^ 1) * 32768];
    const int t1 = (t + 1 < NT) ? t + 1 : 0;  // dummy tail: uniform ledger
    const int t2 = (t + 2 < NT) ? t + 2 : 0;

    sh8 af[8], bfr[4];

    // ==== ph0: af0-3 + bfr (ks0) | stage A-k1(t+1), B-k1(t+1) -> next ====
#pragma unroll
    for (int i = 0; i < 4; ++i)
      af[i] = *(const sh8*)&buf[(wr * 128 + i * 16 + r16) * 32 + kidx];
#pragma unroll
    for (int j = 0; j < 4; ++j)
      bfr[j] = *(const sh8*)&buf[16384 + (wc * 64 + j * 16 + r16) * 32 + kidx];
    SOP(Ag + t1 * 64 + 32, bufN + 8192);
    SOP(Bg + t1 * 64 + 32, bufN + 24576);
    PHASE_SYNC();
    __builtin_amdgcn_s_setprio(1);
#pragma unroll
    for (int i = 0; i < 4; ++i)
#pragma unroll
      for (int j = 0; j < 4; ++j)
        acc[i][j] = __builtin_amdgcn_mfma_f32_16x16x32_bf16(af[i], bfr[j],
                                                            acc[i][j], 0, 0, 0);
    __builtin_amdgcn_s_setprio(0);
    PHASE_SYNC();

    // ==== ph1: af4-7 (ks0) | stage B-k0(t+2) -> cur s2 (freed after ph0) ===
#pragma unroll
    for (int i = 4; i < 8; ++i)
      af[i] = *(const sh8*)&buf[(wr * 128 + i * 16 + r16) * 32 + kidx];
    SOP(Bg + t2 * 64, bufC + 16384);
    PHASE_SYNC();
    __builtin_amdgcn_s_setprio(1);
#pragma unroll
    for (int i = 4; i < 8; ++i)
#pragma unroll
      for (int j = 0; j < 4; ++j)
        acc[i][j] = __builtin_amdgcn_mfma_f32_16x16x32_bf16(af[i], bfr[j],
                                                            acc[i][j], 0, 0, 0);
    __builtin_amdgcn_s_setprio(0);
    PHASE_SYNC();

    // ==== ph2: af0-3 + bfr (ks1) | stage A-k0(t+2) -> cur s0 (freed ph1) ===
#pragma unroll
    for (int i = 0; i < 4; ++i)
      af[i] = *(const sh8*)&buf[8192 + (wr * 128 + i * 16 + r16) * 32 + kidx];
#pragma unroll
    for (int j = 0; j < 4; ++j)
      bfr[j] = *(const sh8*)&buf[24576 + (wc * 64 + j * 16 + r16) * 32 + kidx];
    SOP(Ag + t2 * 64, bufC + 0);
    PHASE_SYNC();
    __builtin_amdgcn_s_setprio(1);
#pragma unroll
    for (int i = 0; i < 4; ++i)
#pragma unroll
      for (int j = 0; j < 4; ++j)
        acc[i][j] = __builtin_amdgcn_mfma_f32_16x16x32_bf16(af[i], bfr[j],
                                                            acc[i][j], 0, 0, 0);
    __builtin_amdgcn_s_setprio(0);
    PHASE_SYNC();

    // ==== ph3: af4-7 (ks1) | single counted drain of the tile ==============
#pragma unroll
    for (int i = 4; i < 8; ++i)
      af[i] = *(const sh8*)&buf[8192 + (wr * 128 + i * 16 + r16) * 32 + kidx];
    // leaves ph1+ph2's 4 loads (t+2 data) in flight; drains ph0's t+1 loads.
    asm volatile("s_waitcnt vmcnt(4)" ::: "memory");
    PHASE_SYNC();
    __builtin_amdgcn_s_setprio(1);
#pragma unroll
    for (int i = 4; i < 8; ++i)
#pragma unroll
      for (int j = 0; j < 4; ++j)
        acc[i][j] = __builtin_amdgcn_mfma_f32_16x16x32_bf16(af[i], bfr[j],
                                                            acc[i][j], 0, 0, 0);
    __builtin_amdgcn_s_setprio(0);
    PHASE_SYNC();
  }
#undef SOP
#undef PHASE_SYNC

  // C-write: j innermost -> contiguous 128B (bf16) / 256B (f32) per row.
  const int crow0 = bm * 256 + wr * 128 + (lane >> 4) * 4;
  const int ccol0 = bn * 256 + wc * 64 + r16;
  float bv[4];
#pragma unroll
  for (int j = 0; j < 4; ++j) bv[j] = bias ? bias[ccol0 + j * 16] : 0.f;
#pragma unroll
  for (int i = 0; i < 8; ++i) {
#pragma unroll
    for (int r = 0; r < 4; ++r) {
      size_t rowoff = (size_t)(crow0 + i * 16 + r) * ldc + ccol0;
#pragma unroll
      for (int j = 0; j < 4; ++j) {
        float v = acc[i][j][r] + bv[j];
        if (OUT_BF16)
          ((short*)Cp)[rowoff + j * 16] = f2bf(v);
        else
          ((float*)Cp)[rowoff + j * 16] = v;
      }
    }
  }
}

// ------------------ fused epilogue: attention + depthwise ------------------
__global__ __launch_bounds__(256) void epilogue(
    const short* __restrict__ qkvx, const float* __restrict__ pos_bias,
    const float* __restrict__ dw0, const float* __restrict__ dw1,
    const float* __restrict__ dw2, const float* __restrict__ dwb,
    short* __restrict__ xcat) {
  __shared__ short sq[4 * 3072];      // 4 tokens x cols 0-3071
  __shared__ short slice[6 * 1024];   // rows t0-1..t0+4 x cols 3072-4095
  int t0 = blockIdx.x * 4;
#pragma unroll
  for (int c = 0; c < 6; ++c) {
    int g = c * 256 + threadIdx.x;    // 1536 chunks = 4 tok x 384
    int tok = (g * 683) >> 18;        // g / 384 for g < 1536
    int off = g - tok * 384;
    ((sh8*)sq)[tok * 384 + off] =
        *(const sh8*)(qkvx + (size_t)(t0 + tok) * 4096 + off * 8);
  }
#pragma unroll
  for (int s = 0; s < 3; ++s) {
    int g = s * 256 + threadIdx.x;    // 768 chunks = 6 rows x 128
    int r = g >> 7, off = g & 127;
    int gr = t0 - 1 + r;
    sh8 v = {};
    if (gr >= 0 && gr < 16384)
      v = *(const sh8*)(qkvx + (size_t)gr * 4096 + 3072 + off * 8);
    ((sh8*)slice)[g] = v;
  }
  __syncthreads();

  int wid = threadIdx.x >> 6, lane = threadIdx.x & 63;
  int t = t0 + wid, n = t & 4095;
  int h = lane >> 2, sub = lane & 3;
  const short* base = sq + wid * 3072 + h * 192;

  float qf[64];
#pragma unroll
  for (int c = 0; c < 8; ++c) {
    sh8 v8 = *(const sh8*)(base + c * 8);
#pragma unroll
    for (int j = 0; j < 8; ++j) qf[c * 8 + j] = bf2f(v8[j]);
  }

  const float* pb = pos_bias + (size_t)n * 256 + h * 16 + sub * 4;
  float p[4];
  float m = -1e30f;
#pragma unroll
  for (int g4 = 0; g4 < 4; ++g4) {
    int g = sub * 4 + g4;
    const short* kk = sq + wid * 3072 + g * 192 + 64;
    float acc = 0.f;
#pragma unroll
    for (int c = 0; c < 8; ++c) {
      sh8 k8 = *(const sh8*)(kk + c * 8);
#pragma unroll
      for (int j = 0; j < 8; ++j) acc += qf[c * 8 + j] * bf2f(k8[j]);
    }
    p[g4] = acc * 0.125f + pb[g4];
    m = fmaxf(m, p[g4]);
  }
  m = fmaxf(m, __shfl_xor(m, 1));
  m = fmaxf(m, __shfl_xor(m, 2));
  float sum = 0.f;
#pragma unroll
  for (int g4 = 0; g4 < 4; ++g4) {
    p[g4] = __expf(p[g4] - m);
    sum += p[g4];
  }
  sum += __shfl_xor(sum, 1);
  sum += __shfl_xor(sum, 2);
  float inv = 1.0f / sum;
#pragma unroll
  for (int g4 = 0; g4 < 4; ++g4) p[g4] *= inv;

  float pall[16];
#pragma unroll
  for (int g = 0; g < 16; ++g)
    pall[g] = __shfl(p[g & 3], (lane & 60) | (g >> 2));

  float o[16] = {};
#pragma unroll
  for (int g = 0; g < 16; ++g) {
    const short* vv = sq + wid * 3072 + g * 192 + 128 + sub * 16;
    sh8 va = *(const sh8*)vv;
    sh8 vb = *(const sh8*)(vv + 8);
#pragma unroll
    for (int j = 0; j < 8; ++j) {
      o[j] += pall[g] * bf2f(va[j]);
      o[8 + j] += pall[g] * bf2f(vb[j]);
    }
  }
  sh8 oa, ob;
#pragma unroll
  for (int j = 0; j < 8; ++j) {
    oa[j] = f2bf(o[j]);
    ob[j] = f2bf(o[8 + j]);
  }
  short* dst = xcat + (size_t)t * 2048 + h * 64 + sub * 16;
  *(sh8*)dst = oa;
  *(sh8*)(dst + 8) = ob;

#pragma unroll
  for (int it = 0; it < 2; ++it) {
    int w = it * 256 + threadIdx.x;   // 512 = 4 tok x 64 col-chunks
    int tok = w >> 7, co = (w & 127) * 8;
    int tt = t0 + tok, nn = tt & 4095;
    const short* lo8 = slice + tok * 1024 + co;
    const short* mi8 = lo8 + 1024;
    const short* hi8 = lo8 + 2048;
    sh8 lo = (nn > 0) ? *(const sh8*)lo8 : sh8{};
    sh8 mi = *(const sh8*)mi8;
    sh8 hi = (nn < 4095) ? *(const sh8*)hi8 : sh8{};
    sh8 out;
#pragma unroll
    for (int j = 0; j < 8; ++j) {
      float v = dw0[co + j] * bf2f(lo[j]) + dw1[co + j] * bf2f(mi[j]) +
                dw2[co + j] * bf2f(hi[j]) + dwb[co + j];
      out[j] = f2bf(v);
    }
    *(sh8*)(xcat + (size_t)tt * 2048 + 1024 + co) = out;
  }
}

// ---------------------------------------------------------------------------
extern "C" void kernel_launch(void* const* d_in, const int* in_sizes, int n_in,
                              void* d_out, int out_size, void* d_ws,
                              size_t ws_size, hipStream_t stream) {
  const float* x      = (const float*)d_in[0];
  const float* qkv_w  = (const float*)d_in[1];
  const float* qkv_b  = (const float*)d_in[2];
  const float* out_w  = (const float*)d_in[3];
  const float* out_b  = (const float*)d_in[4];
  const float* pos_b  = (const float*)d_in[5];
  const float* conv_w = (const float*)d_in[6];
  const float* conv_b = (const float*)d_in[7];
  const float* pw_w   = (const float*)d_in[8];
  const float* pw_b   = (const float*)d_in[9];
  const float* dw_w   = (const float*)d_in[10];
  const float* dw_b   = (const float*)d_in[11];
  const float* tok_w  = (const float*)d_in[12];
  const float* tok_b  = (const float*)d_in[13];

  const int M = 16384;
  char* ws = (char*)d_ws;
  size_t off = 0;
  auto alloc = [&](size_t bytes) -> void* {
    void* p = ws + off;
    off += (bytes + 255) & ~(size_t)255;
    return p;
  };
  short* xb    = (short*)alloc((size_t)M * 1024 * 2);
  short* wbig  = (short*)alloc((size_t)4096 * 1024 * 2);  // [qkv_w^T | W2^T]
  short* wcatT = (short*)alloc((size_t)1024 * 2048 * 2);
  short* convb = (short*)alloc((size_t)1024 * 1024 * 2);
  short* pwb   = (short*)alloc((size_t)1024 * 1024 * 2);
  short* qkvx  = (short*)alloc((size_t)M * 4096 * 2);
  short* xcat  = (short*)alloc((size_t)M * 2048 * 2);
  float* bias4 = (float*)alloc(4096 * 4);
  float* bcat  = (float*)alloc(1024 * 4);
  float* dw0   = (float*)alloc(1024 * 4);
  float* dw1   = (float*)alloc(1024 * 4);
  float* dw2   = (float*)alloc(1024 * 4);
  float* dwb   = (float*)alloc(1024 * 4);
  (void)ws_size; (void)in_sizes; (void)n_in; (void)out_size;

  // weight prep (consolidated launches)
  cvt3<<<9216, 256, 0, stream>>>(x, conv_w, pw_w, xb, convb, pwb);
  transpose_f32_bf16<<<dim3(96, 32), dim3(32, 8), 0, stream>>>(qkv_w, wbig, 3072, 1024, 0);
  transpose2<<<dim3(32, 32, 2), dim3(32, 8), 0, stream>>>(out_w, tok_w, wcatT);
  prep_misc<<<3072, 256, 0, stream>>>(pw_w, conv_b, pw_b, qkv_b, out_b, tok_b,
                                      dw_w, dw_b, bias4, bcat, dw0, dw1, dw2, dwb);
  // W2^T[o][p] = sum_i pw_w[o][i] * conv_w[p][i] -> rows 3072+ of wbig
  gemm128<1><<<dim3(8, 8), 256, 0, stream>>>(pwb, convb, wbig + (size_t)3072 * 1024,
                                             nullptr, 1024, 1024);

  // fused qkv+conv GEMM: [M,1024] @ [4096,1024]^T -> [M,4096]
  gemm8p<1><<<1024, 512, 0, stream>>>(xb, wbig, qkvx, bias4, 1024, 4096, 16);

  // fused attention + depthwise epilogue
  epilogue<<<4096, 256, 0, stream>>>(qkvx, pos_b, dw0, dw1, dw2, dwb, xcat);

  // out = xcat @ [out_w; tok_w] + (out_b + tok_b)
  gemm8p<0><<<256, 512, 0, stream>>>(xcat, wcatT, d_out, bcat, 2048, 1024, 4);
}